// Round 5
// baseline (174.715 us; speedup 1.0000x reference)
//
#include <hip/hip_runtime.h>

// QuantizedActorMLP: x(1M,17) -> quant -> L1(17->64)+quantact -> L2(64->64)+quantact -> L3(64->6)
// Integer-exact bf16 MFMA (ints |n|<=127 exact in bf16, sums < 2^24 exact in fp32 acc).
// R14: concurrency push. R11==R13 (51us) despite 2.5x fewer VMEM requests -> not request-
//      pattern-bound; all pipes <25% busy -> Little's-law concurrency shortfall.
//  - 2-tile supertiles (544 dw + 32 pad = 576), TRIPLE-buffered (depth-2 prefetch):
//    outstanding read bytes/CU 70KB -> 86KB; steady-state s_waitcnt vmcnt(5).
//  - biases moved from 36 VGPRs to LDS tables (9 broadcast ds_read_b128/tile, conflict-
//    free) -> VGPR <=102 via __launch_bounds__(256,5).
//  - LDS/block = 7056 dw = 28.2KB -> 5 blocks/CU x 4 waves = 20 waves/CU (was 16).
//  - staging tail: gld4 with source-clamped lanes (LDS cursor exact, 32-dw pad in buffer;
//    no R12-style overflow; last-supertile source stays in-bounds).
//  Per-tile MFMA core, fragments, quant math verbatim from R11/R13 (absmax 0.0068).

typedef __attribute__((ext_vector_type(8))) short short8;    // MFMA A/B frag (8 bf16)
typedef __attribute__((ext_vector_type(4))) float floatx4;   // MFMA C/D frag
typedef __attribute__((ext_vector_type(4))) unsigned int uint4v;
typedef unsigned int uint;

__device__ __forceinline__ uint f32bits(float v) { union { float f; uint u; } c; c.f = v; return c.u; }
__device__ __forceinline__ short bf16i(float v) { return (short)(f32bits(v) >> 16); }
// pack two integer-valued f32 -> two bf16 in one uint (low = z0): one v_perm_b32
__device__ __forceinline__ uint pack2(float z0, float z1) {
  return __builtin_amdgcn_perm(f32bits(z1), f32bits(z0), 0x07060302u);
}
// round-to-nearest-even integer clamped to [-127,127]: v_med3 + v_rndne
__device__ __forceinline__ float qclamp(float v) {
  return __builtin_rintf(__builtin_amdgcn_fmed3f(v, -127.f, 127.f));
}
__device__ __forceinline__ int imin(int a, int b) { return a < b ? a : b; }

// async global->LDS: LDS dest = (uniform) l + lane*size, global src per-lane.
__device__ __forceinline__ void gld16(const float* g, float* l) {
  __builtin_amdgcn_global_load_lds((__attribute__((address_space(1))) void*)(g),
                                   (__attribute__((address_space(3))) void*)(l),
                                   16, 0, 0);
}
__device__ __forceinline__ void gld4(const float* g, float* l) {
  __builtin_amdgcn_global_load_lds((__attribute__((address_space(1))) void*)(g),
                                   (__attribute__((address_space(3))) void*)(l),
                                   4, 0, 0);
}

__global__ void __launch_bounds__(256, 5) qmlp_fused(
    const float* __restrict__ x,
    const float* __restrict__ W1, const float* __restrict__ b1,
    const float* __restrict__ W2, const float* __restrict__ b2,
    const float* __restrict__ W3, const float* __restrict__ b3,
    float* __restrict__ out, int B)
{
  constexpr float QMAXF = 127.0f;
  constexpr float SCALE = 1.33f;
  const float step  = SCALE / QMAXF;
  const float istep = QMAXF / SCALE;

  // One shared pool, two lifetimes:
  //  preamble: wraw1[0..1088) wraw2[1088..5248) wraw3[5248..5638) redv[5638..5650)
  //  main loop: per-wave x triple-buffer [w*1728 + d*576, +576)   (6912 dw)
  //  persistent: bias tables b1t[6912..6976) b2t[6976..7040) b3t[7040..7056)
  __shared__ __align__(16) float smem[7056];
  float* wraw1 = smem;            // W1 raw, pitch 17
  float* wraw2 = smem + 1088;     // W2 raw, pitch 65 (pad kills gather conflicts)
  float* wraw3 = smem + 5248;     // W3 raw, pitch 65
  float* redv  = smem + 5638;     // per-wave (m1,m2,m3)
  float* b1t   = smem + 6912;     // b1[n]*istep, n=0..63
  float* b2t   = smem + 6976;     // b2[n]*istep
  float* b3t   = smem + 7040;     // b3[n] (n<6) else 0, 16 entries

  const int tid  = threadIdx.x;
  const int lane = tid & 63;
  const int bi   = lane & 15;
  const int q    = lane >> 4;
  const int w    = tid >> 6;

  // ---- coalesced staging of raw weights into LDS, max-abs fused into the load ----
  float m1 = 0.f, m2 = 0.f, m3 = 0.f;
  for (int i = tid; i < 272; i += 256) {                       // W1: 1088 floats = 272 float4
    float4 v = ((const float4*)W1)[i];
    ((float4*)wraw1)[i] = v;
    m1 = fmaxf(m1, fmaxf(fmaxf(fabsf(v.x), fabsf(v.y)), fmaxf(fabsf(v.z), fabsf(v.w))));
  }
  for (int i = tid; i < 1024; i += 256) {                      // W2: 4096 floats = 1024 float4
    float4 v = ((const float4*)W2)[i];
    int r = i >> 4, c0 = (i & 15) * 4;                         // no float4 crosses a 64-row
    float* dst = &wraw2[r * 65 + c0];
    dst[0] = v.x; dst[1] = v.y; dst[2] = v.z; dst[3] = v.w;
    m2 = fmaxf(m2, fmaxf(fmaxf(fabsf(v.x), fabsf(v.y)), fmaxf(fabsf(v.z), fabsf(v.w))));
  }
  for (int i = tid; i < 96; i += 256) {                        // W3: 384 floats = 96 float4
    float4 v = ((const float4*)W3)[i];
    int r = i >> 4, c0 = (i & 15) * 4;
    float* dst = &wraw3[r * 65 + c0];
    dst[0] = v.x; dst[1] = v.y; dst[2] = v.z; dst[3] = v.w;
    m3 = fmaxf(m3, fmaxf(fmaxf(fabsf(v.x), fabsf(v.y)), fmaxf(fabsf(v.z), fabsf(v.w))));
  }
  // bias tables (persistent region, disjoint from wraw*): written once
  if (tid < 64) {
    b1t[tid] = b1[tid] * istep;
    b2t[tid] = b2[tid] * istep;
  }
  if (tid < 16) b3t[tid] = (tid < 6) ? b3[tid] : 0.f;

  #pragma unroll
  for (int off = 32; off > 0; off >>= 1) {
    m1 = fmaxf(m1, __shfl_down(m1, off));
    m2 = fmaxf(m2, __shfl_down(m2, off));
    m3 = fmaxf(m3, __shfl_down(m3, off));
  }
  if (lane == 0) {
    redv[w * 3 + 0] = m1; redv[w * 3 + 1] = m2; redv[w * 3 + 2] = m3;
  }
  __syncthreads();                 // barrier 1: publishes redv + wraw1/2/3 + bias tables
  float s1 = 0.f, s2 = 0.f, s3 = 0.f;
  #pragma unroll
  for (int i = 0; i < 4; ++i) {
    s1 = fmaxf(s1, redv[i * 3 + 0]);
    s2 = fmaxf(s2, redv[i * 3 + 1]);
    s3 = fmaxf(s3, redv[i * 3 + 2]);
  }
  s1 /= QMAXF; s2 /= QMAXF; s3 /= QMAXF;
  const float rs1 = 1.0f / s1, rs2 = 1.0f / s2, rs3 = 1.0f / s3;

  // ---- weight fragments (integer-valued bf16) from LDS (reciprocal-mul quant) ----
  short8 w1f[4];
  #pragma unroll
  for (int t = 0; t < 4; ++t) {
    #pragma unroll
    for (int j = 0; j < 8; ++j) {
      int k = 8 * q + j;
      float wv = (k < 17) ? wraw1[(16 * t + bi) * 17 + k] : 0.f;
      float wi = fminf(fmaxf(rintf(wv * rs1), -QMAXF), QMAXF);
      w1f[t][j] = bf16i(wi);
    }
  }
  // K-permutation: eta = 32s + 16(j>>2) + 4q + (j&3) so layer-L C/D regs feed layer-(L+1) B-frags.
  short8 w2f[4][2];
  #pragma unroll
  for (int t = 0; t < 4; ++t) {
    #pragma unroll
    for (int s = 0; s < 2; ++s) {
      #pragma unroll
      for (int j = 0; j < 8; ++j) {
        int eta = 32 * s + 16 * (j >> 2) + 4 * q + (j & 3);
        float wv = wraw2[(16 * t + bi) * 65 + eta];
        float wi = fminf(fmaxf(rintf(wv * rs2), -QMAXF), QMAXF);
        w2f[t][s][j] = bf16i(wi);
      }
    }
  }
  short8 w3f[2];
  #pragma unroll
  for (int s = 0; s < 2; ++s) {
    #pragma unroll
    for (int j = 0; j < 8; ++j) {
      int eta = 32 * s + 16 * (j >> 2) + 4 * q + (j & 3);
      float wv = (bi < 6) ? wraw3[bi * 65 + eta] : 0.f;
      float wi = fminf(fmaxf(rintf(wv * rs3), -QMAXF), QMAXF);
      w3f[s][j] = bf16i(wi);
    }
  }

  __syncthreads();                 // barrier 2: weight LDS dead -> safe to reuse for x staging

  const float g1 = (s1 * step) * istep;
  const float g2 = (s2 * step) * istep;
  const float sc3 = s3 * step;

  // ---- scalarized work decomposition over 2-tile supertiles ----
  const int ntiles = B >> 4;                                   // 65536
  const int nSup   = ntiles >> 1;                              // 32768 supertiles (32 rows each)
  const int nw     = (int)(gridDim.x << 2);                    // 5120 waves
  const int wid    = __builtin_amdgcn_readfirstlane((int)(blockIdx.x << 2) + w);
  const int nIter  = (nSup + nw - 1) / nw;                     // 7
  const int lastS  = nSup - 1;

  float* xb = smem + w * 1728;                                 // three 576-dword buffers

  const int lane4 = lane * 4;                                  // dword offsets for staging
  const int fbase = bi * 17 + 8 * q;                           // frag base (q<2)
  const int fb2   = bi * 17 + 16;                              // q==2 single element
  const int tlane = 512 + imin(lane, 31);                      // clamped tail source offset

  // stage one supertile (544 dw contiguous + 32-dw pad):
  // 2x dwordx4 (dw 0..511) + 1x dword (lanes write dw 512..575; sources clamped to 543)
  auto stage = [&](int s, float* buf) {
    const float* tp = x + (size_t)s * 544;
    gld16(tp + lane4,        buf);                             // dw   0..255
    gld16(tp + 256 + lane4,  buf + 256);                       // dw 256..511
    gld4 (tp + tlane,        buf + 512);                       // dw 512..575 (543 real, rest dup pad)
  };

  const floatx4 zero4 = {0.f, 0.f, 0.f, 0.f};

  // ---- prologue: fill buffers 0 and 1 (depth-2 prefetch) ----
  stage(imin(wid, lastS),      xb);
  stage(imin(wid + nw, lastS), xb + 576);

  #pragma unroll 1
  for (int it = 0; it < nIter; ++it) {
    const int gs = imin(wid + it * nw, lastS);
    const int bsel = it % 3;
    float* cur = xb + bsel * 576;

    // retire current buffer's 3 loads; keep later stage(s)+stores outstanding
    if      (it == 0) { asm volatile("s_waitcnt vmcnt(3)" ::: "memory"); }
    else if (it == 1) { asm volatile("s_waitcnt vmcnt(4)" ::: "memory"); }
    else              { asm volatile("s_waitcnt vmcnt(5)" ::: "memory"); }

    // issue supertile it+2 into buffer (it+2)%3 (its old contents fully consumed)
    if (it + 2 < nIter) stage(imin(wid + (it + 2) * nw, lastS), xb + ((it + 2) % 3) * 576);

    #pragma unroll 1
    for (int k = 0; k < 2; ++k) {
      float* tb = cur + k * 272;

      // fragment gather from LDS (stride-17-dword: max 2-way bank alias = free)
      float xr[8];
      if (q < 2) {
        #pragma unroll
        for (int j = 0; j < 8; ++j) xr[j] = tb[fbase + j];
      } else if (q == 2) {
        xr[0] = tb[fb2];
        #pragma unroll
        for (int j = 1; j < 8; ++j) xr[j] = 0.f;
      } else {
        #pragma unroll
        for (int j = 0; j < 8; ++j) xr[j] = 0.f;
      }

      // input quant -> B-frag: lane holds Xq[row=bi][k=8q+j]
      uint4v ap;
      #pragma unroll
      for (int jp = 0; jp < 4; ++jp)
        ap[jp] = pack2(qclamp(xr[2 * jp] * istep), qclamp(xr[2 * jp + 1] * istep));
      short8 af = __builtin_bit_cast(short8, ap);

      // L1
      floatx4 c1[4];
      #pragma unroll
      for (int t = 0; t < 4; ++t)
        c1[t] = __builtin_amdgcn_mfma_f32_16x16x32_bf16(w1f[t], af, zero4, 0, 0, 0);

      uint4v h1u[2];
      #pragma unroll
      for (int t = 0; t < 4; ++t) {
        float4 bb = *(const float4*)(b1t + 16 * t + 4 * q);    // broadcast ds_read_b128
        float z0 = qclamp(fmaf(c1[t][0], g1, bb.x));
        float z1 = qclamp(fmaf(c1[t][1], g1, bb.y));
        float z2 = qclamp(fmaf(c1[t][2], g1, bb.z));
        float z3 = qclamp(fmaf(c1[t][3], g1, bb.w));
        h1u[t >> 1][(t & 1) * 2 + 0] = pack2(z0, z1);
        h1u[t >> 1][(t & 1) * 2 + 1] = pack2(z2, z3);
      }
      short8 h1a = __builtin_bit_cast(short8, h1u[0]);
      short8 h1b = __builtin_bit_cast(short8, h1u[1]);

      // L2 (K=64)
      floatx4 c2[4];
      #pragma unroll
      for (int t = 0; t < 4; ++t) {
        c2[t] = __builtin_amdgcn_mfma_f32_16x16x32_bf16(w2f[t][0], h1a, zero4, 0, 0, 0);
        c2[t] = __builtin_amdgcn_mfma_f32_16x16x32_bf16(w2f[t][1], h1b, c2[t], 0, 0, 0);
      }

      uint4v h2u[2];
      #pragma unroll
      for (int t = 0; t < 4; ++t) {
        float4 bb = *(const float4*)(b2t + 16 * t + 4 * q);
        float z0 = qclamp(fmaf(c2[t][0], g2, bb.x));
        float z1 = qclamp(fmaf(c2[t][1], g2, bb.y));
        float z2 = qclamp(fmaf(c2[t][2], g2, bb.z));
        float z3 = qclamp(fmaf(c2[t][3], g2, bb.w));
        h2u[t >> 1][(t & 1) * 2 + 0] = pack2(z0, z1);
        h2u[t >> 1][(t & 1) * 2 + 1] = pack2(z2, z3);
      }
      short8 h2a = __builtin_bit_cast(short8, h2u[0]);
      short8 h2b = __builtin_bit_cast(short8, h2u[1]);

      // L3
      floatx4 c3;
      c3 = __builtin_amdgcn_mfma_f32_16x16x32_bf16(w3f[0], h2a, zero4, 0, 0, 0);
      c3 = __builtin_amdgcn_mfma_f32_16x16x32_bf16(w3f[1], h2b, c3, 0, 0, 0);

      float4 b3v = *(const float4*)(b3t + 4 * q);
      float o0 = fmaf(c3[0], sc3, b3v.x);
      float o1 = fmaf(c3[1], sc3, b3v.y);
      float o2 = fmaf(c3[2], sc3, b3v.z);
      float o3 = fmaf(c3[3], sc3, b3v.w);

      // stage tile-k output IN-PLACE at cur[k*96] (always over input already consumed
      // in program order). ds_write_b64, 24B stride.
      float* ob = cur + k * 96;
      if (q == 0) {
        *(float2*)(ob + bi * 6)     = make_float2(o0, o1);
        *(float2*)(ob + bi * 6 + 2) = make_float2(o2, o3);
      } else if (q == 1) {
        *(float2*)(ob + bi * 6 + 4) = make_float2(o0, o1);
      }
    }

    asm volatile("" ::: "memory");                             // pin LDS write->read order
    // batched store of 32 rows x 6 = 192 dw = 768B contiguous: lanes 0..47 dwordx4
    if (lane < 48) {
      float4 v0 = *(const float4*)(cur + lane4);               // ds_read_b128, linear
      *(float4*)(out + (size_t)gs * 192 + lane4) = v0;
    }
  }
}

extern "C" void kernel_launch(void* const* d_in, const int* in_sizes, int n_in,
                              void* d_out, int out_size, void* d_ws, size_t ws_size,
                              hipStream_t stream) {
  const float* x  = (const float*)d_in[0];
  const float* W1 = (const float*)d_in[1];
  const float* b1 = (const float*)d_in[2];
  const float* W2 = (const float*)d_in[3];
  const float* b2 = (const float*)d_in[4];
  const float* W3 = (const float*)d_in[5];
  const float* b3 = (const float*)d_in[6];
  float* out = (float*)d_out;
  const int B = in_sizes[0] / 17;          // 1048576

  dim3 grid(1280), block(256);             // 5120 waves x 7 super-iterations, 5 blocks/CU
  qmlp_fused<<<grid, block, 0, stream>>>(x, W1, b1, W2, b2, W3, b3, out, B);
}